// Round 7
// baseline (80.792 us; speedup 1.0000x reference)
//
#include <hip/hip_runtime.h>
#include <math.h>

#define B_ 8
#define N_ 128
#define L_ 30
#define D_ 256
#define NEGV -1000000000.0f
#define SCALE 0.0625f   // 1/sqrt(256)

// ---- Kernel 1: q/k projection, 4 rows per block ----
// blocks 0..255: q rows blk*4..+3 ; blocks 256..315: k rows (blk-256)*4..+3
__global__ __launch_bounds__(256) void proj_qk(const float* __restrict__ f_b,
    const float* __restrict__ f_w, const float* __restrict__ Wq,
    const float* __restrict__ bq, const float* __restrict__ Wk,
    const float* __restrict__ bk, float* __restrict__ qmat,
    float* __restrict__ kmat) {
  int blk = blockIdx.x;
  const float* x0; const float* W; const float* bias; float* outp;
  int row0;
  if (blk < 256) {
    row0 = blk * 4;
    x0 = f_b + (size_t)row0 * D_;  W = Wq; bias = bq; outp = qmat + (size_t)row0 * D_;
  } else {
    row0 = (blk - 256) * 4;
    x0 = f_w + (size_t)row0 * D_;  W = Wk; bias = bk; outp = kmat + (size_t)row0 * D_;
  }
  int t = threadIdx.x, wave = t >> 6, lane = t & 63;
  __shared__ float part[4][16][65];

  float4 x4[4];
#pragma unroll
  for (int r = 0; r < 4; ++r)
    x4[r] = ((const float4*)(x0 + (size_t)r * D_))[lane];

  for (int g = 0; g < 4; ++g) {
    int dbase = wave * 64 + g * 16;
#pragma unroll
    for (int r = 0; r < 4; ++r) {
#pragma unroll
      for (int i = 0; i < 16; ++i) {
        float4 w4 = ((const float4*)(W + (size_t)(dbase + i) * D_))[lane];  // L1-hot for r>0
        part[wave][i][lane] = w4.x*x4[r].x + w4.y*x4[r].y + w4.z*x4[r].z + w4.w*x4[r].w;
      }
      float s = 0.f;
#pragma unroll
      for (int j = 0; j < 16; ++j)
        s += part[wave][lane & 15][(lane >> 4) * 16 + j];
      s += __shfl_xor(s, 16);
      s += __shfl_xor(s, 32);
      if (lane < 16)
        outp[(size_t)r * D_ + dbase + lane] = s + bias[dbase + lane];
    }
  }
}

// ---- Kernel 2: aw softmax (over L) + f_bq, per block: one b, 8 n-rows ----
__global__ __launch_bounds__(256) void aw_fbq(const float* __restrict__ f_b,
    const float* __restrict__ f_w, const float* __restrict__ f_s,
    const float* __restrict__ qmask, const float* __restrict__ lmask,
    const float* __restrict__ qmat, const float* __restrict__ kmat,
    float* __restrict__ fbq) {
  int blk = blockIdx.x;           // 128 blocks
  int b = blk >> 4, n0 = (blk & 15) * 8;
  int t = threadIdx.x;

  __shared__ float klds[L_][D_ + 1];
  __shared__ float qlds[8][D_ + 1];
  __shared__ float awl[8][32];

  for (int r = 0; r < 8; ++r)
    qlds[r][t] = qmat[(size_t)(b * N_ + n0 + r) * D_ + t];
  for (int l = 0; l < L_; ++l)
    klds[l][t] = kmat[(size_t)(b * L_ + l) * D_ + t];
  __syncthreads();

  if (t < 240) {
    int r = t / 30, l = t % 30;
    float acc = 0.f;
#pragma unroll 8
    for (int j = 0; j < D_; ++j) acc += qlds[r][j] * klds[l][j];
    float qm = qmask[b * L_ + l];
    awl[r][l] = (qm == 0.f) ? NEGV : acc * SCALE * qm;
  }
  __syncthreads();

  if (t < 8) {
    float mx = -1e30f;
    for (int l = 0; l < L_; ++l) mx = fmaxf(mx, awl[t][l]);
    float s = 0.f;
    for (int l = 0; l < L_; ++l) { float e = __expf(awl[t][l] - mx); awl[t][l] = e; s += e; }
    float inv = 1.f / s;
    for (int l = 0; l < L_; ++l) awl[t][l] *= inv;
  }
  __syncthreads();

  for (int l = 0; l < L_; ++l)
    klds[l][t] = f_w[(size_t)(b * L_ + l) * D_ + t];
  __syncthreads();

  float fsd = f_s[b * D_ + t];
  const float* fbp = f_b + (size_t)(b * N_ + n0) * D_;
  for (int r = 0; r < 8; ++r) {
    float facc = 0.f;
#pragma unroll
    for (int l = 0; l < L_; ++l) facc += awl[r][l] * klds[l][t];
    float lm = lmask[b * N_ + n0 + r];
    fbq[(size_t)(b * N_ + n0 + r) * D_ + t] = fbp[(size_t)r * D_ + t] * (facc * lm + fsd);
  }
}

// ---- Kernel 3: A' row = softmax(f_bq[n].f_bq[m]*scale, masked)*lmask[n] -> ws ----
__global__ __launch_bounds__(256) void a_row(const float* __restrict__ lmask,
    const float* __restrict__ fbq, float* __restrict__ A_ws) {
  int bn = blockIdx.x, b = bn >> 7, n = bn & 127;
  int t = threadIdx.x, w = t >> 6, lane = t & 63;
  __shared__ float part[4][32][65];
  __shared__ float a_lds[N_];
  __shared__ float sm[8];

  float4 qv = ((const float4*)(fbq + (size_t)bn * D_))[lane];
#pragma unroll 8
  for (int i = 0; i < 32; ++i) {
    int m = w * 32 + i;
    float4 v = ((const float4*)(fbq + (size_t)(b * N_ + m) * D_))[lane];
    part[w][i][lane] = v.x*qv.x + v.y*qv.y + v.z*qv.z + v.w*qv.w;
  }
  __syncthreads();
  float s = 0.f;
#pragma unroll
  for (int j = 0; j < 32; ++j)
    s += part[w][lane & 31][(lane >> 5) * 32 + j];
  s += __shfl_xor(s, 32);
  if (lane < 32) a_lds[w * 32 + lane] = s;
  __syncthreads();

  float lmn = lmask[b * N_ + n];
  float e = 0.f;
  if (t < N_) {
    float lm = lmask[b * N_ + t];
    float v = (lm == 0.f) ? NEGV : a_lds[t] * SCALE * lm;
    float mx = v;
#pragma unroll
    for (int off = 32; off >= 1; off >>= 1) mx = fmaxf(mx, __shfl_xor(mx, off));
    if (lane == 0) sm[w] = mx;
  }
  __syncthreads();
  if (t < N_) {
    float lm = lmask[b * N_ + t];
    float v = (lm == 0.f) ? NEGV : a_lds[t] * SCALE * lm;
    float gmax = fmaxf(sm[0], sm[1]);
    e = __expf(v - gmax);
    float ss = e;
#pragma unroll
    for (int off = 32; off >= 1; off >>= 1) ss += __shfl_xor(ss, off);
    if (lane == 0) sm[4 + w] = ss;
  }
  __syncthreads();
  if (t < N_) {
    float tot = sm[4] + sm[5];
    A_ws[(size_t)bn * N_ + t] = e * (lmn / tot);
  }
}

// ---- Kernel 4: compact-front stream. 256 blocks x 1024 thr.
// Block owns 4 consecutive bn regions (512KB of f_m), swept sequentially.
// Within a region, wave w handles m = w + 16*j (j=0..7) -> block front is one
// ~16KB contiguous sliding window; device-wide: 256 dense streams.
__global__ __launch_bounds__(1024, 2) void stream2(const float* __restrict__ f_b,
    const float* __restrict__ f_m, const float* __restrict__ f_s,
    const float* __restrict__ lmask, const float* __restrict__ A_ws,
    float* __restrict__ out) {
  int blk = blockIdx.x;           // 0..255
  int bnbase = blk * 4;
  int b = bnbase >> 7;            // 4 regions share one b (128 % 4 == 0)
  int t = threadIdx.x;            // 0..1023
  int w = t >> 6, lane = t & 63;  // 16 waves

  __shared__ float a_lds[4][N_];                 // 2 KB
  __shared__ float red[16 * 264];                // 16.5 KB, stride 264 floats

  // stage the 4 A-rows
  if (t < 512) {
    int r = t >> 7, m = t & 127;
    a_lds[r][m] = A_ws[(size_t)(bnbase + r) * N_ + m];
  }
  __syncthreads();

  const float4* fbb = (const float4*)(f_b + (size_t)b * N_ * D_);
  float4 fs4 = ((const float4*)(f_s + (size_t)b * D_))[lane];
  const float CLOG = -1.44269504088896f;  // -log2(e)
  float4 cs;
  cs.x = fs4.x * CLOG; cs.y = fs4.y * CLOG;
  cs.z = fs4.z * CLOG; cs.w = fs4.w * CLOG;

  for (int r = 0; r < 4; ++r) {
    int bn = bnbase + r;
    int n  = bn & 127;
    float lmn = lmask[b * N_ + n];
    const float4* fmb = (const float4*)(f_m + (size_t)bn * N_ * D_);

    float4 acc = make_float4(0.f, 0.f, 0.f, 0.f);
    // prefetch j=0
    int m = w;
    float4 fmN = fmb[(size_t)m * 64 + lane];
    float4 fbN = fbb[(size_t)m * 64 + lane];
#pragma unroll
    for (int j = 0; j < 8; ++j) {
      float4 fmC = fmN, fbC = fbN;
      if (j < 7) {
        int mn = w + 16 * (j + 1);
        fmN = fmb[(size_t)mn * 64 + lane];
        fbN = fbb[(size_t)mn * 64 + lane];
      }
      float a = a_lds[r][w + 16 * j];
      float gx = __builtin_amdgcn_rcpf(1.f + __builtin_amdgcn_exp2f(fmC.x * cs.x));
      float gy = __builtin_amdgcn_rcpf(1.f + __builtin_amdgcn_exp2f(fmC.y * cs.y));
      float gz = __builtin_amdgcn_rcpf(1.f + __builtin_amdgcn_exp2f(fmC.z * cs.z));
      float gw = __builtin_amdgcn_rcpf(1.f + __builtin_amdgcn_exp2f(fmC.w * cs.w));
      acc.x += a * (lmn * fbC.x + gx * fmC.x);
      acc.y += a * (lmn * fbC.y + gy * fmC.y);
      acc.z += a * (lmn * fbC.z + gz * fmC.z);
      acc.w += a * (lmn * fbC.w + gw * fmC.w);
    }

    // cross-wave reduce for this region
    float* myrow = red + w * 264;
    ((float4*)myrow)[lane] = acc;   // myrow 16B-aligned (264*4B = 1056B)
    __syncthreads();
    if (t < 256) {
      float s = 0.f;
#pragma unroll
      for (int ww = 0; ww < 16; ++ww) s += red[ww * 264 + t];
      out[(size_t)bn * D_ + t] = f_b[(size_t)(b * N_ + n) * D_ + t] + s;
    }
    __syncthreads();
  }
}

extern "C" void kernel_launch(void* const* d_in, const int* in_sizes, int n_in,
                              void* d_out, int out_size, void* d_ws, size_t ws_size,
                              hipStream_t stream) {
  const float* f_b   = (const float*)d_in[0];
  const float* f_w   = (const float*)d_in[1];
  const float* f_s   = (const float*)d_in[2];
  const float* f_m   = (const float*)d_in[3];
  const float* qmask = (const float*)d_in[4];
  const float* lmask = (const float*)d_in[5];
  const float* Wq    = (const float*)d_in[6];
  const float* bq    = (const float*)d_in[7];
  const float* Wk    = (const float*)d_in[8];
  const float* bk    = (const float*)d_in[9];
  float* out = (float*)d_out;

  float* ws   = (float*)d_ws;
  float* qmat = ws;                        // 262144
  float* kmat = ws + 262144;               // 61440 (pad 65536)
  float* fbq  = ws + 327680;               // 262144
  float* A_ws = ws + 589824;               // 131072

  hipLaunchKernelGGL(proj_qk, dim3(316), dim3(256), 0, stream,
                     f_b, f_w, Wq, bq, Wk, bk, qmat, kmat);
  hipLaunchKernelGGL(aw_fbq, dim3(B_ * N_ / 8), dim3(256), 0, stream,
                     f_b, f_w, f_s, qmask, lmask, qmat, kmat, fbq);
  hipLaunchKernelGGL(a_row, dim3(B_ * N_), dim3(256), 0, stream, lmask, fbq, A_ws);
  hipLaunchKernelGGL(stream2, dim3(256), dim3(1024), 0, stream,
                     f_b, f_m, f_s, lmask, A_ws, out);
}

// Round 8
// 77.269 us; speedup vs baseline: 1.0456x; 1.0456x over previous
//
#include <hip/hip_runtime.h>
#include <math.h>

#define B_ 8
#define N_ 128
#define L_ 30
#define D_ 256
#define NEGV -1000000000.0f
#define SCALE 0.0625f   // 1/sqrt(256)

typedef float f32x4 __attribute__((ext_vector_type(4)));

// ---- Kernel 1: q/k projection, 4 rows per block ----
__global__ __launch_bounds__(256) void proj_qk(const float* __restrict__ f_b,
    const float* __restrict__ f_w, const float* __restrict__ Wq,
    const float* __restrict__ bq, const float* __restrict__ Wk,
    const float* __restrict__ bk, float* __restrict__ qmat,
    float* __restrict__ kmat) {
  int blk = blockIdx.x;
  const float* x0; const float* W; const float* bias; float* outp;
  int row0;
  if (blk < 256) {
    row0 = blk * 4;
    x0 = f_b + (size_t)row0 * D_;  W = Wq; bias = bq; outp = qmat + (size_t)row0 * D_;
  } else {
    row0 = (blk - 256) * 4;
    x0 = f_w + (size_t)row0 * D_;  W = Wk; bias = bk; outp = kmat + (size_t)row0 * D_;
  }
  int t = threadIdx.x, wave = t >> 6, lane = t & 63;
  __shared__ float part[4][16][65];

  float4 x4[4];
#pragma unroll
  for (int r = 0; r < 4; ++r)
    x4[r] = ((const float4*)(x0 + (size_t)r * D_))[lane];

  for (int g = 0; g < 4; ++g) {
    int dbase = wave * 64 + g * 16;
#pragma unroll
    for (int r = 0; r < 4; ++r) {
#pragma unroll
      for (int i = 0; i < 16; ++i) {
        float4 w4 = ((const float4*)(W + (size_t)(dbase + i) * D_))[lane];
        part[wave][i][lane] = w4.x*x4[r].x + w4.y*x4[r].y + w4.z*x4[r].z + w4.w*x4[r].w;
      }
      float s = 0.f;
#pragma unroll
      for (int j = 0; j < 16; ++j)
        s += part[wave][lane & 15][(lane >> 4) * 16 + j];
      s += __shfl_xor(s, 16);
      s += __shfl_xor(s, 32);
      if (lane < 16)
        outp[(size_t)r * D_ + dbase + lane] = s + bias[dbase + lane];
    }
  }
}

// ---- Kernel 2: aw softmax (over L) + f_bq, per block: one b, 8 n-rows ----
__global__ __launch_bounds__(256) void aw_fbq(const float* __restrict__ f_b,
    const float* __restrict__ f_w, const float* __restrict__ f_s,
    const float* __restrict__ qmask, const float* __restrict__ lmask,
    const float* __restrict__ qmat, const float* __restrict__ kmat,
    float* __restrict__ fbq) {
  int blk = blockIdx.x;           // 128 blocks
  int b = blk >> 4, n0 = (blk & 15) * 8;
  int t = threadIdx.x;

  __shared__ float klds[L_][D_ + 1];
  __shared__ float qlds[8][D_ + 1];
  __shared__ float awl[8][32];

  for (int r = 0; r < 8; ++r)
    qlds[r][t] = qmat[(size_t)(b * N_ + n0 + r) * D_ + t];
  for (int l = 0; l < L_; ++l)
    klds[l][t] = kmat[(size_t)(b * L_ + l) * D_ + t];
  __syncthreads();

  if (t < 240) {
    int r = t / 30, l = t % 30;
    float acc = 0.f;
#pragma unroll 8
    for (int j = 0; j < D_; ++j) acc += qlds[r][j] * klds[l][j];
    float qm = qmask[b * L_ + l];
    awl[r][l] = (qm == 0.f) ? NEGV : acc * SCALE * qm;
  }
  __syncthreads();

  if (t < 8) {
    float mx = -1e30f;
    for (int l = 0; l < L_; ++l) mx = fmaxf(mx, awl[t][l]);
    float s = 0.f;
    for (int l = 0; l < L_; ++l) { float e = __expf(awl[t][l] - mx); awl[t][l] = e; s += e; }
    float inv = 1.f / s;
    for (int l = 0; l < L_; ++l) awl[t][l] *= inv;
  }
  __syncthreads();

  for (int l = 0; l < L_; ++l)
    klds[l][t] = f_w[(size_t)(b * L_ + l) * D_ + t];
  __syncthreads();

  float fsd = f_s[b * D_ + t];
  const float* fbp = f_b + (size_t)(b * N_ + n0) * D_;
  for (int r = 0; r < 8; ++r) {
    float facc = 0.f;
#pragma unroll
    for (int l = 0; l < L_; ++l) facc += awl[r][l] * klds[l][t];
    float lm = lmask[b * N_ + n0 + r];
    fbq[(size_t)(b * N_ + n0 + r) * D_ + t] = fbp[(size_t)r * D_ + t] * (facc * lm + fsd);
  }
}

// ---- Kernel 3: A' row softmax AND f_bb = lmn * (A' @ f_b) ----
__global__ __launch_bounds__(256) void a_row_fbb(const float* __restrict__ f_b,
    const float* __restrict__ lmask, const float* __restrict__ fbq,
    float* __restrict__ A_ws, float* __restrict__ fbb_ws) {
  int bn = blockIdx.x, b = bn >> 7, n = bn & 127;
  int t = threadIdx.x, w = t >> 6, lane = t & 63;
  __shared__ float part[4][32][65];
  __shared__ float a_lds[N_];
  __shared__ float sm[8];

  float4 qv = ((const float4*)(fbq + (size_t)bn * D_))[lane];
#pragma unroll 8
  for (int i = 0; i < 32; ++i) {
    int m = w * 32 + i;
    float4 v = ((const float4*)(fbq + (size_t)(b * N_ + m) * D_))[lane];
    part[w][i][lane] = v.x*qv.x + v.y*qv.y + v.z*qv.z + v.w*qv.w;
  }
  __syncthreads();
  float s = 0.f;
#pragma unroll
  for (int j = 0; j < 32; ++j)
    s += part[w][lane & 31][(lane >> 5) * 32 + j];
  s += __shfl_xor(s, 32);
  if (lane < 32) a_lds[w * 32 + lane] = s;
  __syncthreads();

  float lmn = lmask[b * N_ + n];
  float e = 0.f;
  if (t < N_) {
    float lm = lmask[b * N_ + t];
    float v = (lm == 0.f) ? NEGV : a_lds[t] * SCALE * lm;
    float mx = v;
#pragma unroll
    for (int off = 32; off >= 1; off >>= 1) mx = fmaxf(mx, __shfl_xor(mx, off));
    if (lane == 0) sm[w] = mx;
  }
  __syncthreads();
  if (t < N_) {
    float lm = lmask[b * N_ + t];
    float v = (lm == 0.f) ? NEGV : a_lds[t] * SCALE * lm;
    float gmax = fmaxf(sm[0], sm[1]);
    e = __expf(v - gmax);
    float ss = e;
#pragma unroll
    for (int off = 32; off >= 1; off >>= 1) ss += __shfl_xor(ss, off);
    if (lane == 0) sm[4 + w] = ss;
  }
  __syncthreads();
  if (t < N_) {
    float tot = sm[4] + sm[5];
    float av = e * (lmn / tot);
    a_lds[t] = av;
    A_ws[(size_t)bn * N_ + t] = av;
  }
  __syncthreads();

  // f_bb[n,d] = lmn * sum_m A'[n,m] * f_b[b,m,d]   (d = t, coalesced over t)
  {
    const float* fbcol = f_b + (size_t)b * N_ * D_ + t;
    float acc = 0.f;
#pragma unroll 16
    for (int m = 0; m < N_; ++m)
      acc += a_lds[m] * fbcol[(size_t)m * D_];
    fbb_ws[(size_t)bn * D_ + t] = lmn * acc;
  }
}

// ---- Kernel 4: nontemporal f_m stream (pure) ----
// out[bn,:] = f_b[n,:] + fbb_ws[bn,:] + sum_m A'[bn,m]*sigmoid(fm*fs)*fm
__global__ __launch_bounds__(256) void stream_nt(const float* __restrict__ f_b,
    const float* __restrict__ f_m, const float* __restrict__ f_s,
    const float* __restrict__ A_ws, const float* __restrict__ fbb_ws,
    float* __restrict__ out) {
  int bn = blockIdx.x, b = bn >> 7, n = bn & 127;
  int t = threadIdx.x, w = t >> 6, lane = t & 63;

  __shared__ float a_lds[N_];
  __shared__ float4 red[3][64];

  if (t < N_) a_lds[t] = A_ws[(size_t)bn * N_ + t];

  const f32x4* fmb = (const f32x4*)(f_m + (size_t)bn * N_ * D_);
  f32x4 fs4 = ((const f32x4*)(f_s + (size_t)b * D_))[lane];
  const float CLOG = -1.44269504088896f;  // -log2(e)
  f32x4 cs = fs4 * CLOG;
  __syncthreads();

  // wave w handles m = w + 4*i (i = 0..31): block front = 4 consecutive rows.
  f32x4 bufA[8], bufB[8];
  float4 acc = make_float4(0.f, 0.f, 0.f, 0.f);

#pragma unroll
  for (int i = 0; i < 8; ++i)
    bufA[i] = __builtin_nontemporal_load(&fmb[(size_t)(w + 4 * i) * 64 + lane]);

  auto compute8 = [&](f32x4 (&P)[8], int i0) {
#pragma unroll
    for (int i = 0; i < 8; ++i) {
      float a = a_lds[w + 4 * (i0 + i)];
      f32x4 fm4 = P[i];
      float gx = __builtin_amdgcn_rcpf(1.f + __builtin_amdgcn_exp2f(fm4.x * cs.x));
      float gy = __builtin_amdgcn_rcpf(1.f + __builtin_amdgcn_exp2f(fm4.y * cs.y));
      float gz = __builtin_amdgcn_rcpf(1.f + __builtin_amdgcn_exp2f(fm4.z * cs.z));
      float gw = __builtin_amdgcn_rcpf(1.f + __builtin_amdgcn_exp2f(fm4.w * cs.w));
      acc.x += a * (gx * fm4.x);
      acc.y += a * (gy * fm4.y);
      acc.z += a * (gz * fm4.z);
      acc.w += a * (gw * fm4.w);
    }
  };

#pragma unroll
  for (int i = 0; i < 8; ++i)
    bufB[i] = __builtin_nontemporal_load(&fmb[(size_t)(w + 4 * (8 + i)) * 64 + lane]);
  compute8(bufA, 0);
#pragma unroll
  for (int i = 0; i < 8; ++i)
    bufA[i] = __builtin_nontemporal_load(&fmb[(size_t)(w + 4 * (16 + i)) * 64 + lane]);
  compute8(bufB, 8);
#pragma unroll
  for (int i = 0; i < 8; ++i)
    bufB[i] = __builtin_nontemporal_load(&fmb[(size_t)(w + 4 * (24 + i)) * 64 + lane]);
  compute8(bufA, 16);
  compute8(bufB, 24);

  if (w > 0) red[w - 1][lane] = acc;
  __syncthreads();
  if (w == 0) {
#pragma unroll
    for (int j = 0; j < 3; ++j) {
      float4 r4 = red[j][lane];
      acc.x += r4.x; acc.y += r4.y; acc.z += r4.z; acc.w += r4.w;
    }
    const float4* fbb = (const float4*)(f_b + (size_t)b * N_ * D_);
    float4 fbn = fbb[(size_t)n * 64 + lane];
    float4 pb  = ((const float4*)(fbb_ws + (size_t)bn * D_))[lane];
    float4 o;
    o.x = fbn.x + pb.x + acc.x;
    o.y = fbn.y + pb.y + acc.y;
    o.z = fbn.z + pb.z + acc.z;
    o.w = fbn.w + pb.w + acc.w;
    ((float4*)out)[(size_t)bn * 64 + lane] = o;
  }
}

extern "C" void kernel_launch(void* const* d_in, const int* in_sizes, int n_in,
                              void* d_out, int out_size, void* d_ws, size_t ws_size,
                              hipStream_t stream) {
  const float* f_b   = (const float*)d_in[0];
  const float* f_w   = (const float*)d_in[1];
  const float* f_s   = (const float*)d_in[2];
  const float* f_m   = (const float*)d_in[3];
  const float* qmask = (const float*)d_in[4];
  const float* lmask = (const float*)d_in[5];
  const float* Wq    = (const float*)d_in[6];
  const float* bq    = (const float*)d_in[7];
  const float* Wk    = (const float*)d_in[8];
  const float* bk    = (const float*)d_in[9];
  float* out = (float*)d_out;

  float* ws     = (float*)d_ws;
  float* qmat   = ws;                        // 262144
  float* kmat   = ws + 262144;               // 61440 (pad 65536)
  float* fbq    = ws + 327680;               // 262144
  float* A_ws   = ws + 589824;               // 131072
  float* fbb_ws = ws + 720896;               // 262144

  hipLaunchKernelGGL(proj_qk, dim3(316), dim3(256), 0, stream,
                     f_b, f_w, Wq, bq, Wk, bk, qmat, kmat);
  hipLaunchKernelGGL(aw_fbq, dim3(B_ * N_ / 8), dim3(256), 0, stream,
                     f_b, f_w, f_s, qmask, lmask, qmat, kmat, fbq);
  hipLaunchKernelGGL(a_row_fbb, dim3(B_ * N_), dim3(256), 0, stream,
                     f_b, lmask, fbq, A_ws, fbb_ws);
  hipLaunchKernelGGL(stream_nt, dim3(B_ * N_), dim3(256), 0, stream,
                     f_b, f_m, f_s, A_ws, fbb_ws, out);
}